// Round 16
// baseline (249.113 us; speedup 1.0000x reference)
//
#include <hip/hip_runtime.h>

// Problem constants (match reference)
#define K_     1056
#define N_     2112
#define M_     1056   // N - K
#define E_     6336   // M * 6
#define NIE_   5280   // M * 5 info-side edges (the only BP state)
#define CAP_   6336   // padded c2v extent upper bound (stride = d|1 adds <=1/VN)
#define ALL_   7392   // CAP_ + K_ : c2v + marg unified array
#define DV_    5
#define ROW_   6      // edge 6m+5 is the parity VN K+m
#define NSYM_  528
#define NITER_ 20
#define BATCH_ 1024
#define BS_    512    // 8 waves/block

#define LOG2E_ 1.4426950408889634f
#define AVLO_  (1e-6f * LOG2E_)          // |v2c| floor, bits units
#define AVHI_  (20.0f * LOG2E_)          // |v2c| cap,  bits units
#define QC_    0.99999988f               // tanh-domain cap (unchanged)

// stride(d) = d | 1 : always ODD -> coprime with 32 banks -> Phase A's
// wave-uniform-stride segment reads are conflict-free.
__device__ __forceinline__ int seg_stride(int d) { return d | 1; }

// -------------------------------------------------------------------------
// Single kernel, one block per codeword, 512 threads / 8 waves.
//
// R15: __launch_bounds__(512, 6) — NOT 8. At (512,8) the 64-reg unified
// budget split 32 arch + 32 AGPR: hot-loop persistents (vnp[15], od, lr,
// pv, t5 ~= 27 regs) lived in AGPRs, paying v_accvgpr_read/write VALU
// slots every hot-loop access, plus residual scratch spills (R13/R14:
// FETCH 17 MB, WRITE 37 MB). At 6 waves/EU the budget is ~80 VGPRs: all
// live state fits arch regs. Trade: 24 waves/CU instead of 32 — at 92%
// VALU-busy (issue-bound) the extra waves add little; the removed AGPR
// churn + spill slots shrink the VALU stream that IS the bottleneck.
// R14 lesson encoded: LDS bank conflicts are hidden at >90% VALUBusy —
// do not chase them further.
//
// Base-2 LLR domain after demap (LLR_hat = LLR * log2e): v_exp_f32 /
// v_log_f32 are natively 2^x / log2(x). Hard decisions scale-invariant.
//
// LDS (~30 KB): s_all[7392] unified —
//   build: [0..N) staging (bits -> LLR_hat), [N..N+4K) int scratch
//   BP:    [0..CAP) c2v odd-stride padded VN-major segments,
//          [CAP..7392) slot-indexed marginals (K floats)
//
// Structure exploited: H = [A | I].
//   * Parity VN (deg 1): v2c == channel LLR -> per-check constant t5.
//   * Info VNs counting-sorted by degree -> wave-uniform Phase A trips;
//     scan-free segment bases from 32-bin histogram arithmetic.
//   * Old c2v re-read from LDS (single writer per position).
//   * Atomic build order only permutes float accumulation order —
//     validated order-independent in R4-R14 (absmax 0).
//
// CN math (product form, prefix/suffix partial products, bits domain):
//   t = copysign((1-2^-av)/(1+2^-av), v2c);  q_j = t5 * prod_{i!=j} t_i
//   q = med3(q, -QC, QC);  r = log2((1+q)/(1-q))
// -------------------------------------------------------------------------
__global__ __launch_bounds__(BS_, 6) void link_kernel(
    const int*   __restrict__ bits,      // [B,K]
    const int*   __restrict__ a_idx,     // [M,DV]
    const float* __restrict__ points_re, // [16]
    const float* __restrict__ points_im, // [16]
    const float* __restrict__ noise_re,  // [B,NSYM]
    const float* __restrict__ noise_im,  // [B,NSYM]
    const float* __restrict__ ebno_db,   // [1]
    const int*   __restrict__ edge_vn,   // [E]
    float*       __restrict__ out)       // [2,B,K]
{
#pragma clang fp contract(off)
    const int b   = blockIdx.x;
    const int tid = threadIdx.x;

    __shared__ float s_all[ALL_];
    __shared__ float s_pre[16];
    __shared__ float s_pim[16];
    __shared__ int   s_hist[32];
    __shared__ int   s_binStart[32];
    __shared__ int   s_binBase[32];

    float* s_mem  = s_all;               // staging, later c2v [0..CAP)
    float* s_marg = s_all + CAP_;        // BP marginals [CAP..ALL)

    // build scratch aliases [N..N+4K) (inside s_all; demap uses [0..N))
    int* sc        = (int*)(s_all + N_);
    int* s_deg     = sc;                 // [K] degree
    int* s_perm    = sc + K_;            // [K] slot -> v | deg<<16
    int* s_offslot = sc + 2 * K_;        // [K] v -> base | slot<<16
    int* s_cnt     = sc + 3 * K_;        // [K] edge-fill cursors

    if (tid < 16) {
        s_pre[tid] = points_re[tid];
        s_pim[tid] = points_im[tid];
    }
    if (tid < 32) s_hist[tid] = 0;

    const float eb    = ebno_db[0];
    const float no    = 1.0f / ((powf(10.0f, eb / 10.0f) * 0.5f) * 4.0f);
    const float sigma = sqrtf(no / 2.0f);

    // ---- stage info bits (0/1 floats); output0 = bits.astype(f32) ----
    for (int i = tid; i < K_; i += BS_) {
        int v = bits[b * K_ + i];
        s_mem[i] = (float)v;
        out[b * K_ + i] = (float)v;
    }
    __syncthreads();

    // ---- parity: XOR of DV gathered info bits; zero build counters ----
    for (int m = tid; m < M_; m += BS_) {
        float acc = 0.0f;
        #pragma unroll
        for (int d = 0; d < DV_; ++d) acc += s_mem[a_idx[m * DV_ + d]];
        s_mem[K_ + m] = (float)(((int)acc) & 1);
    }
    for (int v = tid; v < K_; v += BS_) { s_deg[v] = 0; s_cnt[v] = 0; }
    __syncthreads();

    // ---- QAM + AWGN + exact APP demap (stores LLR * log2e) ----
    // ---- overlapped: VN degree count (disjoint LDS region)       ----
    for (int s = tid; s < NSYM_; s += BS_) {
        int c0 = (int)s_mem[4 * s + 0];
        int c1 = (int)s_mem[4 * s + 1];
        int c2 = (int)s_mem[4 * s + 2];
        int c3 = (int)s_mem[4 * s + 3];
        int sym = c0 * 8 + c1 * 4 + c2 * 2 + c3;
        float yre = s_pre[sym] + sigma * noise_re[b * NSYM_ + s];
        float yim = s_pim[sym] + sigma * noise_im[b * NSYM_ + s];
        float lg[16];
        #pragma unroll
        for (int p = 0; p < 16; ++p) {
            float dre  = yre - s_pre[p];
            float dim_ = yim - s_pim[p];
            float d2   = dre * dre + dim_ * dim_;
            lg[p] = -d2 / no;
        }
        float llr4[4];
        #pragma unroll
        for (int j = 0; j < 4; ++j) {
            float m0 = -1e30f, m1 = -1e30f;
            #pragma unroll
            for (int p = 0; p < 16; ++p) {
                if (((p >> (3 - j)) & 1) == 0) m0 = fmaxf(m0, lg[p]);
                else                           m1 = fmaxf(m1, lg[p]);
            }
            float sum0 = 0.0f, sum1 = 0.0f;
            #pragma unroll
            for (int p = 0; p < 16; ++p) {
                if (((p >> (3 - j)) & 1) == 0) sum0 += __expf(lg[p] - m0);
                else                           sum1 += __expf(lg[p] - m1);
            }
            llr4[j] = (m0 + __logf(sum0)) - (m1 + __logf(sum1));
        }
        s_mem[4 * s + 0] = llr4[0] * LOG2E_;
        s_mem[4 * s + 1] = llr4[1] * LOG2E_;
        s_mem[4 * s + 2] = llr4[2] * LOG2E_;
        s_mem[4 * s + 3] = llr4[3] * LOG2E_;
    }
    for (int idx = tid; idx < NIE_; idx += BS_) {
        int m = idx / 5, j = idx - m * 5;
        atomicAdd(&s_deg[edge_vn[m * ROW_ + j]], 1);
    }
    __syncthreads();

    // ---- degree histogram -> arithmetic segment bases (scan-free) ----
    for (int v = tid; v < K_; v += BS_) atomicAdd(&s_hist[s_deg[v] & 31], 1);
    __syncthreads();
    if (tid == 0) {
        int accS = 0, accB = 0;
        for (int d = 0; d < 32; ++d) {
            int c = s_hist[d];
            s_binStart[d] = accS;
            s_binBase[d]  = accB;
            s_hist[d]     = accS;        // reuse as sort cursor
            accS += c;
            accB += c * seg_stride(d);   // odd stride -> conflict-free
        }
    }
    __syncthreads();
    for (int v = tid; v < K_; v += BS_) {   // counting sort by degree
        int d    = s_deg[v];
        int slot = atomicAdd(&s_hist[d & 31], 1);
        int base = s_binBase[d] + (slot - s_binStart[d]) * seg_stride(d);
        s_perm[slot]  = v | (d << 16);
        s_offslot[v]  = base | (slot << 16);
    }
    __syncthreads();

    // ---- capture iteration-invariant state in registers ----
    int      pv[3];                      // slot -> VN id
    unsigned od[3];                      // base | deg<<16
    float    lr[3];                      // channel LLR_hat of owned VN
    #pragma unroll
    for (int k = 0; k < 3; ++k) {
        int s = tid + BS_ * k;
        if (s < K_) {
            int w = s_perm[s];
            int v = w & 0xFFFF;
            int d = w >> 16;
            int base = s_binBase[d] + (s - s_binStart[d]) * seg_stride(d);
            pv[k] = v;
            od[k] = (unsigned)base | ((unsigned)d << 16);
            lr[k] = s_mem[v];
        } else { pv[k] = 0; od[k] = 0; lr[k] = 0.0f; }
    }
    float    t5[3];
    unsigned vnp[3][5];                  // slot | pos<<16
    #pragma unroll
    for (int kk = 0; kk < 3; ++kk) {
        int m = tid + BS_ * kk;
        if (m < M_) {
            #pragma unroll
            for (int j = 0; j < 5; ++j) {
                int v = edge_vn[m * ROW_ + j];
                int r = atomicAdd(&s_cnt[v], 1);
                int w = s_offslot[v];
                vnp[kk][j]  = (unsigned)(w >> 16) | ((unsigned)((w & 0xFFFF) + r) << 16);
            }
            float lrP = s_mem[K_ + m];
            float av  = __builtin_amdgcn_fmed3f(fabsf(lrP), AVLO_, AVHI_);
            float e   = exp2f(-av);
            float tm  = __fdividef(1.0f - e, 1.0f + e);
            t5[kk] = copysignf(tm, lrP);
        } else { t5[kk] = 0.0f; }
    }
    __syncthreads();
    // scratch fully consumed -> become the message array
    for (int i = tid; i < CAP_; i += BS_) s_mem[i] = 0.0f;
    __syncthreads();

    // ---- sum-product BP, flooding (all quantities in bits domain) ----
    for (int it = 0; it < NITER_; ++it) {
        // Phase A: slot-indexed marginals; odd-stride segments -> no
        // structured bank conflicts; paired reads -> ds_read2_b32
        #pragma unroll
        for (int k = 0; k < 3; ++k) {
            int s = tid + BS_ * k;
            if (s < K_) {
                int base = (int)(od[k] & 0xFFFFu);
                int dg   = (int)(od[k] >> 16);
                float mg = lr[k];
                int d = 0;
                for (; d + 1 < dg; d += 2) {
                    mg += s_mem[base + d];
                    mg += s_mem[base + d + 1];
                }
                if (d < dg) mg += s_mem[base + d];
                s_marg[s] = mg;
            }
        }
        __syncthreads();
        // Phase B: CN update; old c2v re-read from LDS (intra-thread
        // read-before-write, single writer per position)
        #pragma unroll
        for (int kk = 0; kk < 3; ++kk) {
            int m = tid + BS_ * kk;
            if (m < M_) {
                float tj[5];
                #pragma unroll
                for (int j = 0; j < 5; ++j) {
                    unsigned w = vnp[kk][j];
                    float v2c = s_marg[w & 0xFFFFu] - s_mem[w >> 16];
                    float av  = __builtin_amdgcn_fmed3f(fabsf(v2c), AVLO_, AVHI_);
                    float e   = exp2f(-av);
                    float tm  = __fdividef(1.0f - e, 1.0f + e);
                    tj[j] = copysignf(tm, v2c);
                }
                float qv[5];
                float pr = t5[kk];
                #pragma unroll
                for (int j = 0; j < 5; ++j) { qv[j] = pr; pr *= tj[j]; }
                float sf = 1.0f;
                #pragma unroll
                for (int j = 4; j >= 0; --j) { qv[j] *= sf; sf *= tj[j]; }
                #pragma unroll
                for (int j = 0; j < 5; ++j) {
                    float q = __builtin_amdgcn_fmed3f(qv[j], -QC_, QC_);
                    float r = log2f(__fdividef(1.0f + q, 1.0f - q));
                    s_mem[vnp[kk][j] >> 16] = r;
                }
            }
        }
        __syncthreads();
    }

    // ---- final marginal + hard decision on info VNs ----
    #pragma unroll
    for (int k = 0; k < 3; ++k) {
        int s = tid + BS_ * k;
        if (s < K_) {
            int base = (int)(od[k] & 0xFFFFu);
            int dg   = (int)(od[k] >> 16);
            float mg = lr[k];
            int d = 0;
            for (; d + 1 < dg; d += 2) {
                mg += s_mem[base + d];
                mg += s_mem[base + d + 1];
            }
            if (d < dg) mg += s_mem[base + d];
            out[(size_t)BATCH_ * K_ + b * K_ + pv[k]] = (mg < 0.0f) ? 1.0f : 0.0f;
        }
    }
}

extern "C" void kernel_launch(void* const* d_in, const int* in_sizes, int n_in,
                              void* d_out, int out_size, void* d_ws, size_t ws_size,
                              hipStream_t stream) {
    const int*   bits    = (const int*)  d_in[0];
    const int*   a_idx   = (const int*)  d_in[1];
    // d_in[2] = edge_cn (implicit: contiguous groups of 6) — unused
    const int*   edge_vn = (const int*)  d_in[3];
    const float* pre     = (const float*)d_in[4];
    const float* pim     = (const float*)d_in[5];
    const float* nre     = (const float*)d_in[6];
    const float* nim     = (const float*)d_in[7];
    const float* ebno    = (const float*)d_in[8];

    link_kernel<<<BATCH_, BS_, 0, stream>>>(bits, a_idx, pre, pim, nre, nim,
                                            ebno, edge_vn, (float*)d_out);
}

// Round 17
// 240.710 us; speedup vs baseline: 1.0349x; 1.0349x over previous
//
#include <hip/hip_runtime.h>

// Problem constants (match reference)
#define K_     1056
#define N_     2112
#define M_     1056   // N - K
#define E_     6336   // M * 6
#define NIE_   5280   // M * 5 info-side edges (the only BP state)
#define CAP_   6336   // padded c2v extent upper bound (stride = d|1 adds <=1/VN)
#define ALL_   7392   // CAP_ + K_ : c2v + marg unified array
#define DV_    5
#define ROW_   6      // edge 6m+5 is the parity VN K+m
#define NSYM_  528
#define NITER_ 20
#define BATCH_ 1024
#define BS_    512    // 8 waves/block -> 4 blocks/CU fills all 32 wave slots

#define LOG2E_ 1.4426950408889634f
#define AVLO_  (1e-6f * LOG2E_)          // |v2c| floor, bits units
#define AVHI_  (20.0f * LOG2E_)          // |v2c| cap,  bits units
#define QC_    0.99999988f               // tanh-domain cap (unchanged)

// stride(d) = d | 1 : always ODD -> coprime with 32 banks -> Phase A's
// wave-uniform-stride segment reads are conflict-free.
__device__ __forceinline__ int seg_stride(int d) { return d | 1; }

// -------------------------------------------------------------------------
// Single kernel, one block per codeword, 512 threads / 8 waves (R14 config
// — measured best: 32 waves/CU beats spill-free 24 waves, R15).
//
// R16 change: TWO-PASS streaming demap. R14's one-pass demap kept lg[16]
// live and pushed transient pressure past the 64-reg (32 arch + 32 AGPR)
// envelope at (512,8) -> ~40 MB one-time scratch traffic (FETCH 17 MB,
// WRITE 37 MB). Pass 1 keeps only running maxes m0[4]/m1[4]; pass 2
// recomputes lg per point (5 VALU ops) and accumulates sum0[4]/sum1[4].
// Same values, same ascending-p accumulation order, same __expf/__logf
// calls -> bit-identical LLRs; peak live regs ~60 -> no scratch.
//
// Base-2 LLR domain after demap (LLR_hat = LLR * log2e): v_exp_f32 /
// v_log_f32 are natively 2^x / log2(x). Hard decisions scale-invariant.
//
// LDS (~30 KB): s_all[7392] unified —
//   build: [0..N) staging (bits -> LLR_hat), [N..N+4K) int scratch
//   BP:    [0..CAP) c2v odd-stride padded VN-major segments,
//          [CAP..7392) slot-indexed marginals (K floats)
//
// Structure exploited: H = [A | I].
//   * Parity VN (deg 1): v2c == channel LLR -> per-check constant t5.
//   * Info VNs counting-sorted by degree -> wave-uniform Phase A trips;
//     scan-free segment bases from 32-bin histogram arithmetic.
//   * Old c2v re-read from LDS (single writer per position).
//   * Atomic build order only permutes float accumulation order —
//     validated order-independent in R4-R15 (absmax 0).
//   * R14 lesson: LDS bank conflicts are hidden at >90% VALUBusy.
//
// CN math (product form, prefix/suffix partial products, bits domain):
//   t = copysign((1-2^-av)/(1+2^-av), v2c);  q_j = t5 * prod_{i!=j} t_i
//   q = med3(q, -QC, QC);  r = log2((1+q)/(1-q))
// -------------------------------------------------------------------------
__global__ __launch_bounds__(BS_, 8) void link_kernel(
    const int*   __restrict__ bits,      // [B,K]
    const int*   __restrict__ a_idx,     // [M,DV]
    const float* __restrict__ points_re, // [16]
    const float* __restrict__ points_im, // [16]
    const float* __restrict__ noise_re,  // [B,NSYM]
    const float* __restrict__ noise_im,  // [B,NSYM]
    const float* __restrict__ ebno_db,   // [1]
    const int*   __restrict__ edge_vn,   // [E]
    float*       __restrict__ out)       // [2,B,K]
{
#pragma clang fp contract(off)
    const int b   = blockIdx.x;
    const int tid = threadIdx.x;

    __shared__ float s_all[ALL_];
    __shared__ float s_pre[16];
    __shared__ float s_pim[16];
    __shared__ int   s_hist[32];
    __shared__ int   s_binStart[32];
    __shared__ int   s_binBase[32];

    float* s_mem  = s_all;               // staging, later c2v [0..CAP)
    float* s_marg = s_all + CAP_;        // BP marginals [CAP..ALL)

    // build scratch aliases [N..N+4K) (inside s_all; demap uses [0..N))
    int* sc        = (int*)(s_all + N_);
    int* s_deg     = sc;                 // [K] degree
    int* s_perm    = sc + K_;            // [K] slot -> v | deg<<16
    int* s_offslot = sc + 2 * K_;        // [K] v -> base | slot<<16
    int* s_cnt     = sc + 3 * K_;        // [K] edge-fill cursors

    if (tid < 16) {
        s_pre[tid] = points_re[tid];
        s_pim[tid] = points_im[tid];
    }
    if (tid < 32) s_hist[tid] = 0;

    const float eb    = ebno_db[0];
    const float no    = 1.0f / ((powf(10.0f, eb / 10.0f) * 0.5f) * 4.0f);
    const float sigma = sqrtf(no / 2.0f);

    // ---- stage info bits (0/1 floats); output0 = bits.astype(f32) ----
    for (int i = tid; i < K_; i += BS_) {
        int v = bits[b * K_ + i];
        s_mem[i] = (float)v;
        out[b * K_ + i] = (float)v;
    }
    __syncthreads();

    // ---- parity: XOR of DV gathered info bits; zero build counters ----
    for (int m = tid; m < M_; m += BS_) {
        float acc = 0.0f;
        #pragma unroll
        for (int d = 0; d < DV_; ++d) acc += s_mem[a_idx[m * DV_ + d]];
        s_mem[K_ + m] = (float)(((int)acc) & 1);
    }
    for (int v = tid; v < K_; v += BS_) { s_deg[v] = 0; s_cnt[v] = 0; }
    __syncthreads();

    // ---- QAM + AWGN + exact APP demap, TWO-PASS streaming ----
    // ---- overlapped: VN degree count (disjoint LDS region)   ----
    for (int s = tid; s < NSYM_; s += BS_) {
        int c0 = (int)s_mem[4 * s + 0];
        int c1 = (int)s_mem[4 * s + 1];
        int c2 = (int)s_mem[4 * s + 2];
        int c3 = (int)s_mem[4 * s + 3];
        int sym = c0 * 8 + c1 * 4 + c2 * 2 + c3;
        float yre = s_pre[sym] + sigma * noise_re[b * NSYM_ + s];
        float yim = s_pim[sym] + sigma * noise_im[b * NSYM_ + s];
        // pass 1: per-bit maxes (ascending p, same comparisons as 1-pass)
        float m0[4], m1[4];
        #pragma unroll
        for (int j = 0; j < 4; ++j) { m0[j] = -1e30f; m1[j] = -1e30f; }
        #pragma unroll
        for (int p = 0; p < 16; ++p) {
            float dre  = yre - s_pre[p];
            float dim_ = yim - s_pim[p];
            float lg   = -(dre * dre + dim_ * dim_) / no;
            #pragma unroll
            for (int j = 0; j < 4; ++j) {
                if (((p >> (3 - j)) & 1) == 0) m0[j] = fmaxf(m0[j], lg);
                else                           m1[j] = fmaxf(m1[j], lg);
            }
        }
        // pass 2: recompute lg (identical fp sequence) and accumulate
        float sum0[4] = {0.0f, 0.0f, 0.0f, 0.0f};
        float sum1[4] = {0.0f, 0.0f, 0.0f, 0.0f};
        #pragma unroll
        for (int p = 0; p < 16; ++p) {
            float dre  = yre - s_pre[p];
            float dim_ = yim - s_pim[p];
            float lg   = -(dre * dre + dim_ * dim_) / no;
            #pragma unroll
            for (int j = 0; j < 4; ++j) {
                if (((p >> (3 - j)) & 1) == 0) sum0[j] += __expf(lg - m0[j]);
                else                           sum1[j] += __expf(lg - m1[j]);
            }
        }
        #pragma unroll
        for (int j = 0; j < 4; ++j) {
            float llr = (m0[j] + __logf(sum0[j])) - (m1[j] + __logf(sum1[j]));
            s_mem[4 * s + j] = llr * LOG2E_;
        }
    }
    for (int idx = tid; idx < NIE_; idx += BS_) {
        int m = idx / 5, j = idx - m * 5;
        atomicAdd(&s_deg[edge_vn[m * ROW_ + j]], 1);
    }
    __syncthreads();

    // ---- degree histogram -> arithmetic segment bases (scan-free) ----
    for (int v = tid; v < K_; v += BS_) atomicAdd(&s_hist[s_deg[v] & 31], 1);
    __syncthreads();
    if (tid == 0) {
        int accS = 0, accB = 0;
        for (int d = 0; d < 32; ++d) {
            int c = s_hist[d];
            s_binStart[d] = accS;
            s_binBase[d]  = accB;
            s_hist[d]     = accS;        // reuse as sort cursor
            accS += c;
            accB += c * seg_stride(d);   // odd stride -> conflict-free
        }
    }
    __syncthreads();
    for (int v = tid; v < K_; v += BS_) {   // counting sort by degree
        int d    = s_deg[v];
        int slot = atomicAdd(&s_hist[d & 31], 1);
        int base = s_binBase[d] + (slot - s_binStart[d]) * seg_stride(d);
        s_perm[slot]  = v | (d << 16);
        s_offslot[v]  = base | (slot << 16);
    }
    __syncthreads();

    // ---- capture iteration-invariant state in registers ----
    int      pv[3];                      // slot -> VN id
    unsigned od[3];                      // base | deg<<16
    float    lr[3];                      // channel LLR_hat of owned VN
    #pragma unroll
    for (int k = 0; k < 3; ++k) {
        int s = tid + BS_ * k;
        if (s < K_) {
            int w = s_perm[s];
            int v = w & 0xFFFF;
            int d = w >> 16;
            int base = s_binBase[d] + (s - s_binStart[d]) * seg_stride(d);
            pv[k] = v;
            od[k] = (unsigned)base | ((unsigned)d << 16);
            lr[k] = s_mem[v];
        } else { pv[k] = 0; od[k] = 0; lr[k] = 0.0f; }
    }
    float    t5[3];
    unsigned vnp[3][5];                  // slot | pos<<16
    #pragma unroll
    for (int kk = 0; kk < 3; ++kk) {
        int m = tid + BS_ * kk;
        if (m < M_) {
            #pragma unroll
            for (int j = 0; j < 5; ++j) {
                int v = edge_vn[m * ROW_ + j];
                int r = atomicAdd(&s_cnt[v], 1);
                int w = s_offslot[v];
                vnp[kk][j]  = (unsigned)(w >> 16) | ((unsigned)((w & 0xFFFF) + r) << 16);
            }
            float lrP = s_mem[K_ + m];
            float av  = __builtin_amdgcn_fmed3f(fabsf(lrP), AVLO_, AVHI_);
            float e   = exp2f(-av);
            float tm  = __fdividef(1.0f - e, 1.0f + e);
            t5[kk] = copysignf(tm, lrP);
        } else { t5[kk] = 0.0f; }
    }
    __syncthreads();
    // scratch fully consumed -> become the message array
    for (int i = tid; i < CAP_; i += BS_) s_mem[i] = 0.0f;
    __syncthreads();

    // ---- sum-product BP, flooding (all quantities in bits domain) ----
    for (int it = 0; it < NITER_; ++it) {
        // Phase A: slot-indexed marginals; odd-stride segments -> no
        // structured bank conflicts; paired reads -> ds_read2_b32
        #pragma unroll
        for (int k = 0; k < 3; ++k) {
            int s = tid + BS_ * k;
            if (s < K_) {
                int base = (int)(od[k] & 0xFFFFu);
                int dg   = (int)(od[k] >> 16);
                float mg = lr[k];
                int d = 0;
                for (; d + 1 < dg; d += 2) {
                    mg += s_mem[base + d];
                    mg += s_mem[base + d + 1];
                }
                if (d < dg) mg += s_mem[base + d];
                s_marg[s] = mg;
            }
        }
        __syncthreads();
        // Phase B: CN update; old c2v re-read from LDS (intra-thread
        // read-before-write, single writer per position)
        #pragma unroll
        for (int kk = 0; kk < 3; ++kk) {
            int m = tid + BS_ * kk;
            if (m < M_) {
                float tj[5];
                #pragma unroll
                for (int j = 0; j < 5; ++j) {
                    unsigned w = vnp[kk][j];
                    float v2c = s_marg[w & 0xFFFFu] - s_mem[w >> 16];
                    float av  = __builtin_amdgcn_fmed3f(fabsf(v2c), AVLO_, AVHI_);
                    float e   = exp2f(-av);
                    float tm  = __fdividef(1.0f - e, 1.0f + e);
                    tj[j] = copysignf(tm, v2c);
                }
                float qv[5];
                float pr = t5[kk];
                #pragma unroll
                for (int j = 0; j < 5; ++j) { qv[j] = pr; pr *= tj[j]; }
                float sf = 1.0f;
                #pragma unroll
                for (int j = 4; j >= 0; --j) { qv[j] *= sf; sf *= tj[j]; }
                #pragma unroll
                for (int j = 0; j < 5; ++j) {
                    float q = __builtin_amdgcn_fmed3f(qv[j], -QC_, QC_);
                    float r = log2f(__fdividef(1.0f + q, 1.0f - q));
                    s_mem[vnp[kk][j] >> 16] = r;
                }
            }
        }
        __syncthreads();
    }

    // ---- final marginal + hard decision on info VNs ----
    #pragma unroll
    for (int k = 0; k < 3; ++k) {
        int s = tid + BS_ * k;
        if (s < K_) {
            int base = (int)(od[k] & 0xFFFFu);
            int dg   = (int)(od[k] >> 16);
            float mg = lr[k];
            int d = 0;
            for (; d + 1 < dg; d += 2) {
                mg += s_mem[base + d];
                mg += s_mem[base + d + 1];
            }
            if (d < dg) mg += s_mem[base + d];
            out[(size_t)BATCH_ * K_ + b * K_ + pv[k]] = (mg < 0.0f) ? 1.0f : 0.0f;
        }
    }
}

extern "C" void kernel_launch(void* const* d_in, const int* in_sizes, int n_in,
                              void* d_out, int out_size, void* d_ws, size_t ws_size,
                              hipStream_t stream) {
    const int*   bits    = (const int*)  d_in[0];
    const int*   a_idx   = (const int*)  d_in[1];
    // d_in[2] = edge_cn (implicit: contiguous groups of 6) — unused
    const int*   edge_vn = (const int*)  d_in[3];
    const float* pre     = (const float*)d_in[4];
    const float* pim     = (const float*)d_in[5];
    const float* nre     = (const float*)d_in[6];
    const float* nim     = (const float*)d_in[7];
    const float* ebno    = (const float*)d_in[8];

    link_kernel<<<BATCH_, BS_, 0, stream>>>(bits, a_idx, pre, pim, nre, nim,
                                            ebno, edge_vn, (float*)d_out);
}

// Round 18
// 185.492 us; speedup vs baseline: 1.3430x; 1.2977x over previous
//
#include <hip/hip_runtime.h>

// Problem constants (match reference)
#define K_     1056
#define N_     2112
#define M_     1056   // N - K
#define E_     6336   // M * 6
#define NIE_   5280   // M * 5 info-side edges (the only BP state)
#define CAP_   6336   // padded c2v extent upper bound (stride = d|1 adds <=1/VN)
#define ALL_   7392   // CAP_ + K_ : c2v + marg unified array
#define DV_    5
#define ROW_   6      // edge 6m+5 is the parity VN K+m
#define NSYM_  528
#define NITER_ 20
#define BATCH_ 1024
#define BS_    512    // 8 waves/block -> 4 blocks/CU fills all 32 wave slots

#define LOG2E_ 1.4426950408889634f
#define AVLO_  (1e-6f * LOG2E_)          // |v2c| floor, bits units
#define AVHI_  (20.0f * LOG2E_)          // |v2c| cap,  bits units
#define QC_    0.99999988f               // tanh-domain cap (unchanged)

// stride(d) = d | 1 : always ODD -> coprime with 32 banks -> Phase A's
// wave-uniform-stride segment reads are conflict-free.
__device__ __forceinline__ int seg_stride(int d) { return d | 1; }

// Raw-instruction transcendentals (R17): exp2f/log2f lower to OCML calls
// with denorm/range guards (libm wrappers), inflating the hot loop ~3x vs
// the source-level op count (measured 431K busy cyc/SIMD vs ~152K modeled).
// Our inputs are always normal-range, so the bare instructions (<=1 ULP)
// are safe — the same perturbation envelope validated absmax-0 since R1.
__device__ __forceinline__ float fexp2(float x) { return __builtin_amdgcn_exp2f(x); }
__device__ __forceinline__ float flog2(float x) { return __builtin_amdgcn_logf(x); }
__device__ __forceinline__ float frcp(float x)  { return __builtin_amdgcn_rcpf(x); }

// -------------------------------------------------------------------------
// Single kernel, one block per codeword, 512 threads / 8 waves (R14 config
// — measured best: 32 waves/CU beats spill-free 24 waves, R15).
//
// Base-2 LLR domain after demap (LLR_hat = LLR * log2e): v_exp_f32 /
// v_log_f32 are natively 2^x / log2(x). Hard decisions scale-invariant.
//
// LDS (~30 KB): s_all[7392] unified —
//   build: [0..N) staging (bits -> LLR_hat), [N..N+4K) int scratch
//   BP:    [0..CAP) c2v odd-stride padded VN-major segments,
//          [CAP..7392) slot-indexed marginals (K floats)
//
// Structure exploited: H = [A | I].
//   * Parity VN (deg 1): v2c == channel LLR -> per-check constant t5.
//   * Info VNs counting-sorted by degree -> wave-uniform Phase A trips;
//     scan-free segment bases from 32-bin histogram arithmetic.
//   * Old c2v re-read from LDS (single writer per position).
//   * Atomic build order only permutes float accumulation order —
//     validated order-independent in R4-R16 (absmax 0).
//   * R14/R15 lessons: LDS bank conflicts are hidden at >90% VALUBusy;
//     32 waves/CU beats spill-free 24 waves.
//
// CN math (product form, prefix/suffix partial products, bits domain):
//   t = copysign((1-2^-av)/(1+2^-av), v2c);  q_j = t5 * prod_{i!=j} t_i
//   q = med3(q, -QC, QC);  r = log2((1+q)/(1-q))
// -------------------------------------------------------------------------
__global__ __launch_bounds__(BS_, 8) void link_kernel(
    const int*   __restrict__ bits,      // [B,K]
    const int*   __restrict__ a_idx,     // [M,DV]
    const float* __restrict__ points_re, // [16]
    const float* __restrict__ points_im, // [16]
    const float* __restrict__ noise_re,  // [B,NSYM]
    const float* __restrict__ noise_im,  // [B,NSYM]
    const float* __restrict__ ebno_db,   // [1]
    const int*   __restrict__ edge_vn,   // [E]
    float*       __restrict__ out)       // [2,B,K]
{
#pragma clang fp contract(off)
    const int b   = blockIdx.x;
    const int tid = threadIdx.x;

    __shared__ float s_all[ALL_];
    __shared__ float s_pre[16];
    __shared__ float s_pim[16];
    __shared__ int   s_hist[32];
    __shared__ int   s_binStart[32];
    __shared__ int   s_binBase[32];

    float* s_mem  = s_all;               // staging, later c2v [0..CAP)
    float* s_marg = s_all + CAP_;        // BP marginals [CAP..ALL)

    // build scratch aliases [N..N+4K) (inside s_all; demap uses [0..N))
    int* sc        = (int*)(s_all + N_);
    int* s_deg     = sc;                 // [K] degree
    int* s_perm    = sc + K_;            // [K] slot -> v | deg<<16
    int* s_offslot = sc + 2 * K_;        // [K] v -> base | slot<<16
    int* s_cnt     = sc + 3 * K_;        // [K] edge-fill cursors

    if (tid < 16) {
        s_pre[tid] = points_re[tid];
        s_pim[tid] = points_im[tid];
    }
    if (tid < 32) s_hist[tid] = 0;

    const float eb    = ebno_db[0];
    const float no    = 1.0f / ((powf(10.0f, eb / 10.0f) * 0.5f) * 4.0f);
    const float sigma = sqrtf(no / 2.0f);

    // ---- stage info bits (0/1 floats); output0 = bits.astype(f32) ----
    for (int i = tid; i < K_; i += BS_) {
        int v = bits[b * K_ + i];
        s_mem[i] = (float)v;
        out[b * K_ + i] = (float)v;
    }
    __syncthreads();

    // ---- parity: XOR of DV gathered info bits; zero build counters ----
    for (int m = tid; m < M_; m += BS_) {
        float acc = 0.0f;
        #pragma unroll
        for (int d = 0; d < DV_; ++d) acc += s_mem[a_idx[m * DV_ + d]];
        s_mem[K_ + m] = (float)(((int)acc) & 1);
    }
    for (int v = tid; v < K_; v += BS_) { s_deg[v] = 0; s_cnt[v] = 0; }
    __syncthreads();

    // ---- QAM + AWGN + exact APP demap, two-pass streaming ----
    // ---- overlapped: VN degree count (disjoint LDS region)   ----
    for (int s = tid; s < NSYM_; s += BS_) {
        int c0 = (int)s_mem[4 * s + 0];
        int c1 = (int)s_mem[4 * s + 1];
        int c2 = (int)s_mem[4 * s + 2];
        int c3 = (int)s_mem[4 * s + 3];
        int sym = c0 * 8 + c1 * 4 + c2 * 2 + c3;
        float yre = s_pre[sym] + sigma * noise_re[b * NSYM_ + s];
        float yim = s_pim[sym] + sigma * noise_im[b * NSYM_ + s];
        // pass 1: per-bit maxes (ascending p, same comparisons as 1-pass)
        float m0[4], m1[4];
        #pragma unroll
        for (int j = 0; j < 4; ++j) { m0[j] = -1e30f; m1[j] = -1e30f; }
        #pragma unroll
        for (int p = 0; p < 16; ++p) {
            float dre  = yre - s_pre[p];
            float dim_ = yim - s_pim[p];
            float lg   = -(dre * dre + dim_ * dim_) / no;
            #pragma unroll
            for (int j = 0; j < 4; ++j) {
                if (((p >> (3 - j)) & 1) == 0) m0[j] = fmaxf(m0[j], lg);
                else                           m1[j] = fmaxf(m1[j], lg);
            }
        }
        // pass 2: recompute lg (identical fp sequence) and accumulate
        float sum0[4] = {0.0f, 0.0f, 0.0f, 0.0f};
        float sum1[4] = {0.0f, 0.0f, 0.0f, 0.0f};
        #pragma unroll
        for (int p = 0; p < 16; ++p) {
            float dre  = yre - s_pre[p];
            float dim_ = yim - s_pim[p];
            float lg   = -(dre * dre + dim_ * dim_) / no;
            #pragma unroll
            for (int j = 0; j < 4; ++j) {
                if (((p >> (3 - j)) & 1) == 0) sum0[j] += __expf(lg - m0[j]);
                else                           sum1[j] += __expf(lg - m1[j]);
            }
        }
        #pragma unroll
        for (int j = 0; j < 4; ++j) {
            float llr = (m0[j] + __logf(sum0[j])) - (m1[j] + __logf(sum1[j]));
            s_mem[4 * s + j] = llr * LOG2E_;
        }
    }
    for (int idx = tid; idx < NIE_; idx += BS_) {
        int m = idx / 5, j = idx - m * 5;
        atomicAdd(&s_deg[edge_vn[m * ROW_ + j]], 1);
    }
    __syncthreads();

    // ---- degree histogram -> arithmetic segment bases (scan-free) ----
    for (int v = tid; v < K_; v += BS_) atomicAdd(&s_hist[s_deg[v] & 31], 1);
    __syncthreads();
    if (tid == 0) {
        int accS = 0, accB = 0;
        for (int d = 0; d < 32; ++d) {
            int c = s_hist[d];
            s_binStart[d] = accS;
            s_binBase[d]  = accB;
            s_hist[d]     = accS;        // reuse as sort cursor
            accS += c;
            accB += c * seg_stride(d);   // odd stride -> conflict-free
        }
    }
    __syncthreads();
    for (int v = tid; v < K_; v += BS_) {   // counting sort by degree
        int d    = s_deg[v];
        int slot = atomicAdd(&s_hist[d & 31], 1);
        int base = s_binBase[d] + (slot - s_binStart[d]) * seg_stride(d);
        s_perm[slot]  = v | (d << 16);
        s_offslot[v]  = base | (slot << 16);
    }
    __syncthreads();

    // ---- capture iteration-invariant state in registers ----
    int      pv[3];                      // slot -> VN id
    unsigned od[3];                      // base | deg<<16
    float    lr[3];                      // channel LLR_hat of owned VN
    #pragma unroll
    for (int k = 0; k < 3; ++k) {
        int s = tid + BS_ * k;
        if (s < K_) {
            int w = s_perm[s];
            int v = w & 0xFFFF;
            int d = w >> 16;
            int base = s_binBase[d] + (s - s_binStart[d]) * seg_stride(d);
            pv[k] = v;
            od[k] = (unsigned)base | ((unsigned)d << 16);
            lr[k] = s_mem[v];
        } else { pv[k] = 0; od[k] = 0; lr[k] = 0.0f; }
    }
    float    t5[3];
    unsigned vnp[3][5];                  // slot | pos<<16
    #pragma unroll
    for (int kk = 0; kk < 3; ++kk) {
        int m = tid + BS_ * kk;
        if (m < M_) {
            #pragma unroll
            for (int j = 0; j < 5; ++j) {
                int v = edge_vn[m * ROW_ + j];
                int r = atomicAdd(&s_cnt[v], 1);
                int w = s_offslot[v];
                vnp[kk][j]  = (unsigned)(w >> 16) | ((unsigned)((w & 0xFFFF) + r) << 16);
            }
            float lrP = s_mem[K_ + m];
            float av  = __builtin_amdgcn_fmed3f(fabsf(lrP), AVLO_, AVHI_);
            float e   = fexp2(-av);
            float tm  = (1.0f - e) * frcp(1.0f + e);
            t5[kk] = copysignf(tm, lrP);
        } else { t5[kk] = 0.0f; }
    }
    __syncthreads();
    // scratch fully consumed -> become the message array
    for (int i = tid; i < CAP_; i += BS_) s_mem[i] = 0.0f;
    __syncthreads();

    // ---- sum-product BP, flooding (all quantities in bits domain) ----
    for (int it = 0; it < NITER_; ++it) {
        // Phase A: slot-indexed marginals; odd-stride segments -> no
        // structured bank conflicts; paired reads -> ds_read2_b32
        #pragma unroll
        for (int k = 0; k < 3; ++k) {
            int s = tid + BS_ * k;
            if (s < K_) {
                int base = (int)(od[k] & 0xFFFFu);
                int dg   = (int)(od[k] >> 16);
                float mg = lr[k];
                int d = 0;
                for (; d + 1 < dg; d += 2) {
                    mg += s_mem[base + d];
                    mg += s_mem[base + d + 1];
                }
                if (d < dg) mg += s_mem[base + d];
                s_marg[s] = mg;
            }
        }
        __syncthreads();
        // Phase B: CN update; old c2v re-read from LDS (intra-thread
        // read-before-write, single writer per position); bare v_exp/
        // v_log/v_rcp transcendentals
        #pragma unroll
        for (int kk = 0; kk < 3; ++kk) {
            int m = tid + BS_ * kk;
            if (m < M_) {
                float tj[5];
                #pragma unroll
                for (int j = 0; j < 5; ++j) {
                    unsigned w = vnp[kk][j];
                    float v2c = s_marg[w & 0xFFFFu] - s_mem[w >> 16];
                    float av  = __builtin_amdgcn_fmed3f(fabsf(v2c), AVLO_, AVHI_);
                    float e   = fexp2(-av);
                    float tm  = (1.0f - e) * frcp(1.0f + e);
                    tj[j] = copysignf(tm, v2c);
                }
                float qv[5];
                float pr = t5[kk];
                #pragma unroll
                for (int j = 0; j < 5; ++j) { qv[j] = pr; pr *= tj[j]; }
                float sf = 1.0f;
                #pragma unroll
                for (int j = 4; j >= 0; --j) { qv[j] *= sf; sf *= tj[j]; }
                #pragma unroll
                for (int j = 0; j < 5; ++j) {
                    float q = __builtin_amdgcn_fmed3f(qv[j], -QC_, QC_);
                    float r = flog2((1.0f + q) * frcp(1.0f - q));
                    s_mem[vnp[kk][j] >> 16] = r;
                }
            }
        }
        __syncthreads();
    }

    // ---- final marginal + hard decision on info VNs ----
    #pragma unroll
    for (int k = 0; k < 3; ++k) {
        int s = tid + BS_ * k;
        if (s < K_) {
            int base = (int)(od[k] & 0xFFFFu);
            int dg   = (int)(od[k] >> 16);
            float mg = lr[k];
            int d = 0;
            for (; d + 1 < dg; d += 2) {
                mg += s_mem[base + d];
                mg += s_mem[base + d + 1];
            }
            if (d < dg) mg += s_mem[base + d];
            out[(size_t)BATCH_ * K_ + b * K_ + pv[k]] = (mg < 0.0f) ? 1.0f : 0.0f;
        }
    }
}

extern "C" void kernel_launch(void* const* d_in, const int* in_sizes, int n_in,
                              void* d_out, int out_size, void* d_ws, size_t ws_size,
                              hipStream_t stream) {
    const int*   bits    = (const int*)  d_in[0];
    const int*   a_idx   = (const int*)  d_in[1];
    // d_in[2] = edge_cn (implicit: contiguous groups of 6) — unused
    const int*   edge_vn = (const int*)  d_in[3];
    const float* pre     = (const float*)d_in[4];
    const float* pim     = (const float*)d_in[5];
    const float* nre     = (const float*)d_in[6];
    const float* nim     = (const float*)d_in[7];
    const float* ebno    = (const float*)d_in[8];

    link_kernel<<<BATCH_, BS_, 0, stream>>>(bits, a_idx, pre, pim, nre, nim,
                                            ebno, edge_vn, (float*)d_out);
}